// Round 1
// baseline (1742.799 us; speedup 1.0000x reference)
//
#include <hip/hip_runtime.h>
#include <stdint.h>

typedef int i32x4 __attribute__((ext_vector_type(4)));

#define TWO_LOG2E 2.8853900817779268f

// ---------------- ws layout ----------------
// [0,8)            : thrbits[2] (uint, atomicMax of |w| bits)
// [4096, +16MB)    : Xq  [32768][512] int8
// then             : WriT [1024][512] int8  (n = dir*512 + j, k = i)
// then             : WrhT [2][512][512] int8 (row j, col i)
#define WS_XQ_OFF   4096
#define XQ_BYTES    ((size_t)32768 * 512)
#define WRIT_BYTES  ((size_t)1024 * 512)
#define WRHT_BYTES  ((size_t)2 * 512 * 512)

// ---------------- threshold = max |w| over [w_ri; w_rh] per direction ----------------
__global__ __launch_bounds__(256) void k_absmax(const float* __restrict__ wri_f,
                                                const float* __restrict__ wrh_f,
                                                const float* __restrict__ wri_b,
                                                const float* __restrict__ wrh_b,
                                                unsigned* thrbits) {
    int dir = blockIdx.y;
    const float* a = dir ? wri_b : wri_f;
    const float* c = dir ? wrh_b : wrh_f;
    float m = 0.f;
    for (int i = blockIdx.x * 256 + threadIdx.x; i < 512 * 512; i += gridDim.x * 256) {
        m = fmaxf(m, fabsf(a[i]));
        m = fmaxf(m, fabsf(c[i]));
    }
    __shared__ float red[256];
    red[threadIdx.x] = m;
    __syncthreads();
    for (int s = 128; s > 0; s >>= 1) {
        if (threadIdx.x < s) red[threadIdx.x] = fmaxf(red[threadIdx.x], red[threadIdx.x + s]);
        __syncthreads();
    }
    if (threadIdx.x == 0) atomicMax(&thrbits[dir], __float_as_uint(red[0]));
}

// ---------------- quantize weights + transpose (WT[j][i] = round(W[i][j]/s)) ----------------
__global__ __launch_bounds__(256) void k_quant_w(const float* __restrict__ wri_f,
                                                 const float* __restrict__ wrh_f,
                                                 const float* __restrict__ wri_b,
                                                 const float* __restrict__ wrh_b,
                                                 const unsigned* __restrict__ thrbits,
                                                 signed char* __restrict__ writ,
                                                 signed char* __restrict__ wrht) {
    int id = blockIdx.x;             // 256 blocks
    int dir = id & 1;
    int which = (id >> 1) & 1;       // 0 = ri, 1 = rh
    int tile = id >> 2;              // 0..63  (8x8 tiles of 64x64)
    int ti = tile >> 3, tj = tile & 7;
    const float* src = which ? (dir ? wrh_b : wrh_f) : (dir ? wri_b : wri_f);
    signed char* dst = which ? (wrht + (size_t)dir * 512 * 512) : (writ + (size_t)dir * 512 * 512);
    float s = __uint_as_float(thrbits[dir]) / 127.0f;
    __shared__ signed char t8[64][68];
    int tx = threadIdx.x & 63, ty = threadIdx.x >> 6;
    int i0 = ti * 64, j0 = tj * 64;
#pragma unroll
    for (int r = 0; r < 16; ++r) {
        int il = r * 4 + ty;
        float w = src[(size_t)(i0 + il) * 512 + j0 + tx];
        float q = rintf(w / s);
        q = fminf(fmaxf(q, -127.f), 127.f);
        t8[il][tx] = (signed char)(int)q;
    }
    __syncthreads();
#pragma unroll
    for (int r = 0; r < 16; ++r) {
        int jl = r * 4 + ty;
        dst[(size_t)(j0 + jl) * 512 + i0 + tx] = t8[tx][jl];  // WT[j][i]
    }
}

// ---------------- quantize inputs: xq = round(clip(x,-1,1)*127) ----------------
__global__ __launch_bounds__(256) void k_quant_x(const float* __restrict__ x,
                                                 signed char* __restrict__ xq) {
    int i = blockIdx.x * 256 + threadIdx.x;   // one float4 per thread, 16384 blocks
    float4 v = ((const float4*)x)[i];
    int q0 = (int)rintf(fminf(fmaxf(v.x, -1.f), 1.f) * 127.f);
    int q1 = (int)rintf(fminf(fmaxf(v.y, -1.f), 1.f) * 127.f);
    int q2 = (int)rintf(fminf(fmaxf(v.z, -1.f), 1.f) * 127.f);
    int q3 = (int)rintf(fminf(fmaxf(v.w, -1.f), 1.f) * 127.f);
    ((int*)xq)[i] = (q0 & 255) | ((q1 & 255) << 8) | ((q2 & 255) << 16) | ((q3 & 255) << 24);
}

// ---------------- GEMM: out[t*16+b][n] = (Xq . WriT[n]) * gs2 + b[n]*2log2e ----------------
// A = Xq [32768][512] i8, B = WriT [1024][512] i8 (row n, col k). No LDS: frags direct from L2/L3.
__global__ __launch_bounds__(256, 2) void k_gemm_xif(const signed char* __restrict__ xq,
                                                     const signed char* __restrict__ writ,
                                                     const float* __restrict__ b_f,
                                                     const float* __restrict__ b_b,
                                                     const unsigned* __restrict__ thrbits,
                                                     float* __restrict__ out) {
    int bid = blockIdx.x;        // 2048 = 256 Mtiles * 8 Ntiles
    int mt8 = bid >> 3;
    int nt8 = bid & 7;
    int w = threadIdx.x >> 6, lane = threadIdx.x & 63;
    int l15 = lane & 15, q = lane >> 4;
    int M0 = mt8 * 128 + (w >> 1) * 64;
    int N0 = nt8 * 128 + (w & 1) * 64;
    int dir = N0 >> 9;
    float thr = __uint_as_float(thrbits[dir]);
    float gs2 = thr * (TWO_LOG2E / (127.f * 127.f));
    const float* bp = dir ? b_b : b_f;
    float bi2[4];
#pragma unroll
    for (int nt = 0; nt < 4; ++nt)
        bi2[nt] = bp[(N0 & 511) + nt * 16 + l15] * TWO_LOG2E;

    i32x4 acc[4][4];
#pragma unroll
    for (int mt = 0; mt < 4; ++mt)
#pragma unroll
        for (int nt = 0; nt < 4; ++nt)
            acc[mt][nt] = (i32x4){0, 0, 0, 0};

#pragma unroll
    for (int kb = 0; kb < 8; ++kb) {
        i32x4 af[4], bf[4];
#pragma unroll
        for (int mt = 0; mt < 4; ++mt)
            af[mt] = *(const i32x4*)(xq + (size_t)(M0 + mt * 16 + l15) * 512 + kb * 64 + q * 16);
#pragma unroll
        for (int nt = 0; nt < 4; ++nt)
            bf[nt] = *(const i32x4*)(writ + (size_t)(N0 + nt * 16 + l15) * 512 + kb * 64 + q * 16);
#pragma unroll
        for (int mt = 0; mt < 4; ++mt)
#pragma unroll
            for (int nt = 0; nt < 4; ++nt)
                acc[mt][nt] = __builtin_amdgcn_mfma_i32_16x16x64_i8(af[mt], bf[nt], acc[mt][nt], 0, 0, 0);
    }
#pragma unroll
    for (int mt = 0; mt < 4; ++mt)
#pragma unroll
        for (int nt = 0; nt < 4; ++nt)
#pragma unroll
            for (int r = 0; r < 4; ++r) {
                int row = M0 + mt * 16 + q * 4 + r;
                int col = N0 + nt * 16 + l15;
                out[(size_t)row * 1024 + col] = fmaf((float)acc[mt][nt][r], gs2, bi2[nt]);
            }
}

// ---------------- persistent recurrence: 1 WG per (dir, batch), 32 WGs ----------------
// gate_arg = acc*gs2 + XiF (XiF read from out, overwritten with h afterwards)
// h127 = rint(127*tanh) = rint(127 - 254 / (1 + exp2(arg)))
__global__ __launch_bounds__(512, 2) void k_rnn(const signed char* __restrict__ wrht,
                                                const unsigned* __restrict__ thrbits,
                                                float* __restrict__ out) {
    int bid = blockIdx.x;           // 32
    int dir = bid >> 4, batch = bid & 15;
    int w = threadIdx.x >> 6, lane = threadIdx.x & 63;
    int l15 = lane & 15, q = lane >> 4;
    int n0 = w * 64;
    float thr = __uint_as_float(thrbits[dir]);
    float gs2 = thr * (TWO_LOG2E / (127.f * 127.f));
    const signed char* wq = wrht + (size_t)dir * 512 * 512;

    // B fragments of Wrh resident in VGPRs: 8 kb x 4 ntiles x 16B
    i32x4 bf[8][4];
#pragma unroll
    for (int kb = 0; kb < 8; ++kb)
#pragma unroll
        for (int nt = 0; nt < 4; ++nt)
            bf[kb][nt] = *(const i32x4*)(wq + (size_t)(n0 + nt * 16 + l15) * 512 + kb * 64 + q * 16);

    __shared__ __align__(16) signed char st[2][16][528];  // double-buffered state, padded rows
    for (int i = threadIdx.x; i < 2 * 16 * 528; i += 512) ((signed char*)st)[i] = 0;
    __syncthreads();

    int t0 = dir ? 2047 : 0;
    float xi[4], xin[4];
    size_t xrow0 = ((size_t)t0 * 16 + batch) * 1024 + (size_t)dir * 512;
#pragma unroll
    for (int nt = 0; nt < 4; ++nt) xi[nt] = out[xrow0 + n0 + nt * 16 + l15];

    int pp = 0;
    for (int step = 0; step < 2048; ++step) {
        int tcur = dir ? (2047 - step) : step;
        int nstep = (step + 1 < 2048) ? (step + 1) : step;
        int tnext = dir ? (2047 - nstep) : nstep;
        size_t xrowN = ((size_t)tnext * 16 + batch) * 1024 + (size_t)dir * 512;
        // prefetch next step's XiF (hides HBM latency under MFMAs)
#pragma unroll
        for (int nt = 0; nt < 4; ++nt) xin[nt] = out[xrowN + n0 + nt * 16 + l15];

        // A fragments from state LDS (row 0 = real batch row, rows 1-15 zero)
        i32x4 af[8];
#pragma unroll
        for (int kb = 0; kb < 8; ++kb)
            af[kb] = *(const i32x4*)&st[pp][l15][kb * 64 + q * 16];

        float houtf[4];
        int hbyte[4];
#pragma unroll
        for (int nt = 0; nt < 4; ++nt) {
            i32x4 acc = (i32x4){0, 0, 0, 0};
#pragma unroll
            for (int kb = 0; kb < 8; ++kb)
                acc = __builtin_amdgcn_mfma_i32_16x16x64_i8(af[kb], bf[kb][nt], acc, 0, 0, 0);
            // valid element: row 0 -> reg 0, lanes 0-15 (others compute garbage harmlessly)
            float arg = fmaf((float)acc[0], gs2, xi[nt]);
            float e = __builtin_amdgcn_exp2f(arg);
            float r = __builtin_amdgcn_rcpf(1.0f + e);
            float h127 = rintf(fmaf(r, -254.0f, 127.0f));
            houtf[nt] = h127 * (1.0f / 127.0f);
            hbyte[nt] = (int)h127;
        }

        size_t orow = ((size_t)tcur * 16 + batch) * 1024 + (size_t)dir * 512;
        if (lane < 16) {
#pragma unroll
            for (int nt = 0; nt < 4; ++nt) {
                out[orow + n0 + nt * 16 + lane] = houtf[nt];
                st[pp ^ 1][0][n0 + nt * 16 + lane] = (signed char)hbyte[nt];
            }
        }
#pragma unroll
        for (int nt = 0; nt < 4; ++nt) xi[nt] = xin[nt];
        __syncthreads();   // next-step state (other buffer) ready for all waves
        pp ^= 1;
    }
}

extern "C" void kernel_launch(void* const* d_in, const int* in_sizes, int n_in,
                              void* d_out, int out_size, void* d_ws, size_t ws_size,
                              hipStream_t stream) {
    const float* x     = (const float*)d_in[0];
    const float* wri_f = (const float*)d_in[1];
    const float* wrh_f = (const float*)d_in[2];
    const float* b_f   = (const float*)d_in[3];
    const float* wri_b = (const float*)d_in[4];
    const float* wrh_b = (const float*)d_in[5];
    const float* b_b   = (const float*)d_in[6];
    float* out = (float*)d_out;
    char* ws = (char*)d_ws;

    size_t need = WS_XQ_OFF + XQ_BYTES + WRIT_BYTES + WRHT_BYTES;
    if (ws_size < need) return;  // fail loudly rather than corrupt

    unsigned* thrbits = (unsigned*)ws;
    signed char* xq   = (signed char*)(ws + WS_XQ_OFF);
    signed char* writ = xq + XQ_BYTES;
    signed char* wrht = writ + WRIT_BYTES;

    hipMemsetAsync(thrbits, 0, 8, stream);
    k_absmax<<<dim3(64, 2), 256, 0, stream>>>(wri_f, wrh_f, wri_b, wrh_b, thrbits);
    k_quant_w<<<256, 256, 0, stream>>>(wri_f, wrh_f, wri_b, wrh_b, thrbits, writ, wrht);
    k_quant_x<<<16384, 256, 0, stream>>>(x, xq);
    k_gemm_xif<<<2048, 256, 0, stream>>>(xq, writ, b_f, b_b, thrbits, out);
    k_rnn<<<32, 512, 0, stream>>>(wrht, thrbits, out);
}

// Round 2
// 1622.343 us; speedup vs baseline: 1.0742x; 1.0742x over previous
//
#include <hip/hip_runtime.h>
#include <stdint.h>

typedef int i32x4 __attribute__((ext_vector_type(4)));

#define TWO_LOG2E 2.8853900817779268f

// ---------------- ws layout ----------------
// [0,8)            : thrbits[2] (uint, atomicMax of |w| bits)
// [4096, +16MB)    : Xq  [32768][512] int8
// then             : WriT [1024][512] int8  (n = dir*512 + j, k = i)
// then             : WrhT [2][512][512] int8 (row j, col i)
#define WS_XQ_OFF   4096
#define XQ_BYTES    ((size_t)32768 * 512)
#define WRIT_BYTES  ((size_t)1024 * 512)
#define WRHT_BYTES  ((size_t)2 * 512 * 512)

static __device__ __forceinline__ int dot4(int a, int b, int c) {
#if __has_builtin(__builtin_amdgcn_sdot4)
    return __builtin_amdgcn_sdot4(a, b, c, false);
#else
    int r = c;
    r += (int)(signed char)(a) * (int)(signed char)(b);
    r += (int)(signed char)(a >> 8) * (int)(signed char)(b >> 8);
    r += (int)(signed char)(a >> 16) * (int)(signed char)(b >> 16);
    r += (int)(signed char)(a >> 24) * (int)(signed char)(b >> 24);
    return r;
#endif
}

// ---------------- threshold = max |w| over [w_ri; w_rh] per direction ----------------
__global__ __launch_bounds__(256) void k_absmax(const float* __restrict__ wri_f,
                                                const float* __restrict__ wrh_f,
                                                const float* __restrict__ wri_b,
                                                const float* __restrict__ wrh_b,
                                                unsigned* thrbits) {
    int dir = blockIdx.y;
    const float* a = dir ? wri_b : wri_f;
    const float* c = dir ? wrh_b : wrh_f;
    float m = 0.f;
    for (int i = blockIdx.x * 256 + threadIdx.x; i < 512 * 512; i += gridDim.x * 256) {
        m = fmaxf(m, fabsf(a[i]));
        m = fmaxf(m, fabsf(c[i]));
    }
    __shared__ float red[256];
    red[threadIdx.x] = m;
    __syncthreads();
    for (int s = 128; s > 0; s >>= 1) {
        if (threadIdx.x < s) red[threadIdx.x] = fmaxf(red[threadIdx.x], red[threadIdx.x + s]);
        __syncthreads();
    }
    if (threadIdx.x == 0) atomicMax(&thrbits[dir], __float_as_uint(red[0]));
}

// ---------------- quantize weights + transpose (WT[j][i] = round(W[i][j]/s)) ----------------
__global__ __launch_bounds__(256) void k_quant_w(const float* __restrict__ wri_f,
                                                 const float* __restrict__ wrh_f,
                                                 const float* __restrict__ wri_b,
                                                 const float* __restrict__ wrh_b,
                                                 const unsigned* __restrict__ thrbits,
                                                 signed char* __restrict__ writ,
                                                 signed char* __restrict__ wrht) {
    int id = blockIdx.x;             // 256 blocks
    int dir = id & 1;
    int which = (id >> 1) & 1;       // 0 = ri, 1 = rh
    int tile = id >> 2;              // 0..63  (8x8 tiles of 64x64)
    int ti = tile >> 3, tj = tile & 7;
    const float* src = which ? (dir ? wrh_b : wrh_f) : (dir ? wri_b : wri_f);
    signed char* dst = which ? (wrht + (size_t)dir * 512 * 512) : (writ + (size_t)dir * 512 * 512);
    float s = __uint_as_float(thrbits[dir]) / 127.0f;
    __shared__ signed char t8[64][68];
    int tx = threadIdx.x & 63, ty = threadIdx.x >> 6;
    int i0 = ti * 64, j0 = tj * 64;
#pragma unroll
    for (int r = 0; r < 16; ++r) {
        int il = r * 4 + ty;
        float w = src[(size_t)(i0 + il) * 512 + j0 + tx];
        float q = rintf(w / s);
        q = fminf(fmaxf(q, -127.f), 127.f);
        t8[il][tx] = (signed char)(int)q;
    }
    __syncthreads();
#pragma unroll
    for (int r = 0; r < 16; ++r) {
        int jl = r * 4 + ty;
        dst[(size_t)(j0 + jl) * 512 + i0 + tx] = t8[tx][jl];  // WT[j][i]
    }
}

// ---------------- quantize inputs: xq = round(clip(x,-1,1)*127) ----------------
__global__ __launch_bounds__(256) void k_quant_x(const float* __restrict__ x,
                                                 signed char* __restrict__ xq) {
    int i = blockIdx.x * 256 + threadIdx.x;   // one float4 per thread, 16384 blocks
    float4 v = ((const float4*)x)[i];
    int q0 = (int)rintf(fminf(fmaxf(v.x, -1.f), 1.f) * 127.f);
    int q1 = (int)rintf(fminf(fmaxf(v.y, -1.f), 1.f) * 127.f);
    int q2 = (int)rintf(fminf(fmaxf(v.z, -1.f), 1.f) * 127.f);
    int q3 = (int)rintf(fminf(fmaxf(v.w, -1.f), 1.f) * 127.f);
    ((int*)xq)[i] = (q0 & 255) | ((q1 & 255) << 8) | ((q2 & 255) << 16) | ((q3 & 255) << 24);
}

// ---------------- GEMM: out[t*16+b][n] = (Xq . WriT[n]) * gs2 + b[n]*2log2e ----------------
__global__ __launch_bounds__(256, 2) void k_gemm_xif(const signed char* __restrict__ xq,
                                                     const signed char* __restrict__ writ,
                                                     const float* __restrict__ b_f,
                                                     const float* __restrict__ b_b,
                                                     const unsigned* __restrict__ thrbits,
                                                     float* __restrict__ out) {
    int bid = blockIdx.x;        // 2048 = 256 Mtiles * 8 Ntiles
    int mt8 = bid >> 3;
    int nt8 = bid & 7;
    int w = threadIdx.x >> 6, lane = threadIdx.x & 63;
    int l15 = lane & 15, q = lane >> 4;
    int M0 = mt8 * 128 + (w >> 1) * 64;
    int N0 = nt8 * 128 + (w & 1) * 64;
    int dir = N0 >> 9;
    float thr = __uint_as_float(thrbits[dir]);
    float gs2 = thr * (TWO_LOG2E / (127.f * 127.f));
    const float* bp = dir ? b_b : b_f;
    float bi2[4];
#pragma unroll
    for (int nt = 0; nt < 4; ++nt)
        bi2[nt] = bp[(N0 & 511) + nt * 16 + l15] * TWO_LOG2E;

    i32x4 acc[4][4];
#pragma unroll
    for (int mt = 0; mt < 4; ++mt)
#pragma unroll
        for (int nt = 0; nt < 4; ++nt)
            acc[mt][nt] = (i32x4){0, 0, 0, 0};

#pragma unroll
    for (int kb = 0; kb < 8; ++kb) {
        i32x4 af[4], bf[4];
#pragma unroll
        for (int mt = 0; mt < 4; ++mt)
            af[mt] = *(const i32x4*)(xq + (size_t)(M0 + mt * 16 + l15) * 512 + kb * 64 + q * 16);
#pragma unroll
        for (int nt = 0; nt < 4; ++nt)
            bf[nt] = *(const i32x4*)(writ + (size_t)(N0 + nt * 16 + l15) * 512 + kb * 64 + q * 16);
#pragma unroll
        for (int mt = 0; mt < 4; ++mt)
#pragma unroll
            for (int nt = 0; nt < 4; ++nt)
                acc[mt][nt] = __builtin_amdgcn_mfma_i32_16x16x64_i8(af[mt], bf[nt], acc[mt][nt], 0, 0, 0);
    }
#pragma unroll
    for (int mt = 0; mt < 4; ++mt)
#pragma unroll
        for (int nt = 0; nt < 4; ++nt)
#pragma unroll
            for (int r = 0; r < 4; ++r) {
                int row = M0 + mt * 16 + q * 4 + r;
                int col = N0 + nt * 16 + l15;
                out[(size_t)row * 1024 + col] = fmaf((float)acc[mt][nt][r], gs2, bi2[nt]);
            }
}

// ---------------- persistent recurrence: 1 WG per (dir, batch), 32 WGs ----------------
// dot4 GEMV: each of 512 lanes owns one output column n; its W_rh row (512 B) lives
// in 128 VGPRs; the 512-B int8 state is broadcast from LDS (same-address b128 reads).
// gate_arg = acc*gs2 + XiF (XiF read from out, overwritten with h afterwards)
// h127 = rint(127*tanh) = rint(127 - 254 / (1 + exp2(arg)))
__global__ __launch_bounds__(512, 2) void k_rnn(const signed char* __restrict__ wrht,
                                                const unsigned* __restrict__ thrbits,
                                                float* __restrict__ out) {
    int bid = blockIdx.x;           // 32
    int dir = bid >> 4, batch = bid & 15;
    int n = threadIdx.x;            // this lane's output column
    float thr = __uint_as_float(thrbits[dir]);
    float gs2 = thr * (TWO_LOG2E / (127.f * 127.f));
    const signed char* wq = wrht + (size_t)dir * 512 * 512 + (size_t)n * 512;

    // W row resident in VGPRs: 32 x i32x4 = 128 VGPRs, static indexing only
    i32x4 w[32];
#pragma unroll
    for (int i = 0; i < 32; ++i)
        w[i] = *(const i32x4*)(wq + i * 16);

    __shared__ __align__(16) signed char st[2][512];
    if (threadIdx.x < 256) ((int*)st)[threadIdx.x] = 0;
    __syncthreads();

    int t0 = dir ? 2047 : 0;
    const long long rowstride = (long long)(dir ? -1 : 1) * 16 * 1024;
    float* prow = out + (size_t)t0 * 16 * 1024 + (size_t)batch * 1024 + (size_t)dir * 512 + n;

    float xi = *prow;
    int pp = 0;
    for (int step = 0; step < 2048; ++step) {
        // prefetch next step's XiF (hides HBM/L2 latency under the dot4 stream)
        float* pnext = prow + ((step + 1 < 2048) ? rowstride : 0);
        float xin = *pnext;

        int acc0 = 0, acc1 = 0, acc2 = 0, acc3 = 0;
#pragma unroll
        for (int kb = 0; kb < 32; ++kb) {
            i32x4 s4 = *(const i32x4*)&st[pp][kb * 16];  // broadcast read, conflict-free
            acc0 = dot4(w[kb][0], s4[0], acc0);
            acc1 = dot4(w[kb][1], s4[1], acc1);
            acc2 = dot4(w[kb][2], s4[2], acc2);
            acc3 = dot4(w[kb][3], s4[3], acc3);
        }
        int acc = (acc0 + acc1) + (acc2 + acc3);

        float arg = fmaf((float)acc, gs2, xi);
        float e = __builtin_amdgcn_exp2f(arg);
        float r = __builtin_amdgcn_rcpf(1.0f + e);
        float h127 = rintf(fmaf(r, -254.0f, 127.0f));
        *prow = h127 * (1.0f / 127.0f);                  // h out (coalesced, all 64 lanes)
        st[pp ^ 1][n] = (signed char)(int)h127;          // next state byte

        xi = xin;
        prow = pnext;
        // LDS-only barrier: don't drain vmcnt (the h-store can stay in flight)
        asm volatile("s_waitcnt lgkmcnt(0)" ::: "memory");
        __builtin_amdgcn_s_barrier();
        __builtin_amdgcn_sched_barrier(0);
        pp ^= 1;
    }
}

extern "C" void kernel_launch(void* const* d_in, const int* in_sizes, int n_in,
                              void* d_out, int out_size, void* d_ws, size_t ws_size,
                              hipStream_t stream) {
    const float* x     = (const float*)d_in[0];
    const float* wri_f = (const float*)d_in[1];
    const float* wrh_f = (const float*)d_in[2];
    const float* b_f   = (const float*)d_in[3];
    const float* wri_b = (const float*)d_in[4];
    const float* wrh_b = (const float*)d_in[5];
    const float* b_b   = (const float*)d_in[6];
    float* out = (float*)d_out;
    char* ws = (char*)d_ws;

    size_t need = WS_XQ_OFF + XQ_BYTES + WRIT_BYTES + WRHT_BYTES;
    if (ws_size < need) return;

    unsigned* thrbits = (unsigned*)ws;
    signed char* xq   = (signed char*)(ws + WS_XQ_OFF);
    signed char* writ = xq + XQ_BYTES;
    signed char* wrht = writ + WRIT_BYTES;

    hipMemsetAsync(thrbits, 0, 8, stream);
    k_absmax<<<dim3(64, 2), 256, 0, stream>>>(wri_f, wrh_f, wri_b, wrh_b, thrbits);
    k_quant_w<<<256, 256, 0, stream>>>(wri_f, wrh_f, wri_b, wrh_b, thrbits, writ, wrht);
    k_quant_x<<<16384, 256, 0, stream>>>(x, xq);
    k_gemm_xif<<<2048, 256, 0, stream>>>(xq, writ, b_f, b_b, thrbits, out);
    k_rnn<<<32, 512, 0, stream>>>(wrht, thrbits, out);
}